// Round 7
// baseline (71.642 us; speedup 1.0000x reference)
//
#include <hip/hip_runtime.h>

#define XX 36
#define XY 10
#define ROW 396               // XX * (XY + 1)
#define RPB 4                 // rows per block = 1 row per wave
#define BLK 256               // 4 waves -> 8 blocks/CU = 32 waves/CU
#define EPB (RPB * ROW)       // 1584 floats = 6336 B per tile
#define RV4 (ROW / 4)         // 99 float4 per row

typedef float f4 __attribute__((ext_vector_type(4)));

// wave-local ordering fence: drain this wave's outstanding LDS ops and
// forbid compiler reordering across it. DS ops of one wave execute in
// order, so this replaces __syncthreads() for wave-private tiles.
#define WAVE_LDS_FENCE() asm volatile("s_waitcnt lgkmcnt(0)" ::: "memory")

// strongest no-allocate store hint on gfx950: nontemporal + system scope.
// Goal: keep the 207.6 MB output stream from evicting the L3-resident input.
__device__ __forceinline__ void store_nt_bypass(f4* dst, f4 v) {
    asm volatile("global_store_dwordx4 %0, %1, off nt sc0 sc1"
                 :: "v"(dst), "v"(v) : "memory");
}

__global__ __launch_bounds__(BLK, 8)
void lorenz96_fs_kernel(const float* __restrict__ u,
                        const float* __restrict__ param,
                        float* __restrict__ out) {
    __shared__ float si[EPB];   // input tiles,  one 396-float slice per wave
    __shared__ float so[EPB];   // output tiles, one 396-float slice per wave

    const int tid = threadIdx.x;
    const int w   = tid >> 6;          // wave id 0..3
    const int l   = tid & 63;          // lane

    const float F = param[0];
    const float h = param[1];
    const float c = param[2];
    const float b = param[3];

    const long long rowg = (long long)blockIdx.x * RPB + w;   // this wave's row
    const long long gbase = rowg * ROW;

    // ---- wave loads its row: 99 float4, coalesced, CACHED (L3-resident) ----
    const f4* __restrict__ in4 = (const f4*)(u + gbase);
    f4* si4 = (f4*)(si + w * ROW);
    si4[l] = in4[l];
    if (l < RV4 - 64) si4[l + 64] = in4[l + 64];

    WAVE_LDS_FENCE();

    // ---- lanes 0..35: one (group i) each -> dx[i] + dy[i][0..9] ----
    if (l < XX) {
        const int i = l;
        const float* __restrict__ row  = si + w * ROW;
        float*       __restrict__ orow = so + w * ROW;

        const float xi  = row[i];
        const float xp1 = row[(i + 1 < XX) ? i + 1 : i + 1 - XX];
        const float xm1 = row[(i >= 1) ? i - 1 : i + XX - 1];
        const float xm2 = row[(i >= 2) ? i - 2 : i + XX - 2];

        float y[XY];
        const float* __restrict__ yr = row + XX + i * XY;
        #pragma unroll
        for (int j = 0; j < XY; ++j) y[j] = yr[j];

        float sum = 0.0f;
        #pragma unroll
        for (int j = 0; j < XY; ++j) sum += y[j];

        orow[i] = (xp1 - xm2) * xm1 - xi + F - (h * c * 0.1f) * sum;

        const float add = h * 0.1f * xi;
        const float cb  = c * b;
        float* __restrict__ oyr = orow + XX + i * XY;
        #pragma unroll
        for (int j = 0; j < XY; ++j) {
            const int jp1 = (j + 1) % XY;          // compile-time under unroll
            const int jp2 = (j + 2) % XY;
            const int jm1 = (j + XY - 1) % XY;
            oyr[j] = c * (add - y[j]) - cb * y[jp1] * (y[jp2] - y[jm1]);
        }
    }

    WAVE_LDS_FENCE();

    // ---- wave stores its row: 99 float4, coalesced, NT+system-scope ----
    const f4* __restrict__ so4 = (const f4*)(so + w * ROW);
    f4* __restrict__ o4 = (f4*)(out + gbase);
    store_nt_bypass(&o4[l], so4[l]);
    if (l < RV4 - 64) store_nt_bypass(&o4[l + 64], so4[l + 64]);
}

extern "C" void kernel_launch(void* const* d_in, const int* in_sizes, int n_in,
                              void* d_out, int out_size, void* d_ws, size_t ws_size,
                              hipStream_t stream) {
    // inputs: d_in[0] = t (int scalar, unused), d_in[1] = u (f32), d_in[2] = param (f32 x4)
    const float* u     = (const float*)d_in[1];
    const float* param = (const float*)d_in[2];
    float* out         = (float*)d_out;

    const int nrows   = in_sizes[1] / ROW;     // 131072
    const int nblocks = nrows / RPB;           // 32768

    lorenz96_fs_kernel<<<nblocks, BLK, 0, stream>>>(u, param, out);
}

// Round 8
// 69.609 us; speedup vs baseline: 1.0292x; 1.0292x over previous
//
#include <hip/hip_runtime.h>

#define XX 36
#define XY 10
#define ROW 396               // XX * (XY + 1)
#define RPB 4                 // rows per block = 1 row per wave
#define BLK 256               // 4 waves -> 8 blocks/CU = 32 waves/CU
#define EPB (RPB * ROW)       // 1584 floats = 6336 B per tile
#define RV4 (ROW / 4)         // 99 float4 per row

typedef float f4 __attribute__((ext_vector_type(4)));

// wave-local ordering fence: drain this wave's outstanding LDS ops and
// forbid compiler reordering across it. DS ops of one wave execute in
// order, so this replaces __syncthreads() for wave-private tiles.
#define WAVE_LDS_FENCE() asm volatile("s_waitcnt lgkmcnt(0)" ::: "memory")

__global__ __launch_bounds__(BLK, 8)
void lorenz96_fs_kernel(const float* __restrict__ u,
                        const float* __restrict__ param,
                        float* __restrict__ out) {
    __shared__ float si[EPB];   // input tiles,  one 396-float slice per wave
    __shared__ float so[EPB];   // output tiles, one 396-float slice per wave

    const int tid = threadIdx.x;
    const int w   = tid >> 6;          // wave id 0..3
    const int l   = tid & 63;          // lane

    const float F = param[0];
    const float h = param[1];
    const float c = param[2];
    const float b = param[3];

    const long long rowg = (long long)blockIdx.x * RPB + w;   // this wave's row
    const long long gbase = rowg * ROW;

    // ---- wave loads its row: 99 float4, coalesced, NONTEMPORAL ----
    // Flip of round 6: the READ stream gets nt (don't claim LLC capacity);
    // the output (207.6 MB) fits the 256 MB LLC entirely and should stay
    // dirty-resident across graph replays -> HBM writes collapse.
    const f4* __restrict__ in4 = (const f4*)(u + gbase);
    f4* si4 = (f4*)(si + w * ROW);
    si4[l] = __builtin_nontemporal_load(&in4[l]);
    if (l < RV4 - 64) si4[l + 64] = __builtin_nontemporal_load(&in4[l + 64]);

    WAVE_LDS_FENCE();

    // ---- lanes 0..35: one (group i) each -> dx[i] + dy[i][0..9] ----
    if (l < XX) {
        const int i = l;
        const float* __restrict__ row  = si + w * ROW;
        float*       __restrict__ orow = so + w * ROW;

        const float xi  = row[i];
        const float xp1 = row[(i + 1 < XX) ? i + 1 : i + 1 - XX];
        const float xm1 = row[(i >= 1) ? i - 1 : i + XX - 1];
        const float xm2 = row[(i >= 2) ? i - 2 : i + XX - 2];

        float y[XY];
        const float* __restrict__ yr = row + XX + i * XY;
        #pragma unroll
        for (int j = 0; j < XY; ++j) y[j] = yr[j];

        float sum = 0.0f;
        #pragma unroll
        for (int j = 0; j < XY; ++j) sum += y[j];

        orow[i] = (xp1 - xm2) * xm1 - xi + F - (h * c * 0.1f) * sum;

        const float add = h * 0.1f * xi;
        const float cb  = c * b;
        float* __restrict__ oyr = orow + XX + i * XY;
        #pragma unroll
        for (int j = 0; j < XY; ++j) {
            const int jp1 = (j + 1) % XY;          // compile-time under unroll
            const int jp2 = (j + 2) % XY;
            const int jm1 = (j + XY - 1) % XY;
            oyr[j] = c * (add - y[j]) - cb * y[jp1] * (y[jp2] - y[jm1]);
        }
    }

    WAVE_LDS_FENCE();

    // ---- wave stores its row: 99 float4, coalesced, CACHED ----
    const f4* __restrict__ so4 = (const f4*)(so + w * ROW);
    f4* __restrict__ o4 = (f4*)(out + gbase);
    o4[l] = so4[l];
    if (l < RV4 - 64) o4[l + 64] = so4[l + 64];
}

extern "C" void kernel_launch(void* const* d_in, const int* in_sizes, int n_in,
                              void* d_out, int out_size, void* d_ws, size_t ws_size,
                              hipStream_t stream) {
    // inputs: d_in[0] = t (int scalar, unused), d_in[1] = u (f32), d_in[2] = param (f32 x4)
    const float* u     = (const float*)d_in[1];
    const float* param = (const float*)d_in[2];
    float* out         = (float*)d_out;

    const int nrows   = in_sizes[1] / ROW;     // 131072
    const int nblocks = nrows / RPB;           // 32768

    lorenz96_fs_kernel<<<nblocks, BLK, 0, stream>>>(u, param, out);
}

// Round 9
// 68.781 us; speedup vs baseline: 1.0416x; 1.0120x over previous
//
#include <hip/hip_runtime.h>

#define XX 36
#define XY 10
#define ROW 396               // XX * (XY + 1)
#define RPB 4                 // rows per tile = 1 row per wave
#define BLK 256               // 4 waves -> 8 blocks/CU = 32 waves/CU
#define EPB (RPB * ROW)       // 1584 floats per tile
#define RV4 (ROW / 4)         // 99 float4 per row
#define NBLK 2048             // 256 CU x 8 blocks/CU, all co-resident
#define NROWS 131072
#define NTILES (NROWS / RPB)  // 32768
#define TPB (NTILES / NBLK)   // 16 tiles per block (chunked)

typedef float f4 __attribute__((ext_vector_type(4)));

// wave-local ordering fence: DS ops of one wave execute in order, so this
// replaces __syncthreads() for wave-private tiles.
#define WAVE_LDS_FENCE() asm volatile("s_waitcnt lgkmcnt(0)" ::: "memory")

__global__ __launch_bounds__(BLK, 8)
void lorenz96_fs_kernel(const float* __restrict__ u,
                        const float* __restrict__ param,
                        float* __restrict__ out) {
    __shared__ float si[EPB];   // input tiles,  one 396-float slice per wave
    __shared__ float so[EPB];   // output tiles, one 396-float slice per wave

    const int tid = threadIdx.x;
    const int w   = tid >> 6;          // wave id 0..3
    const int l   = tid & 63;          // lane
    const bool second = (l < RV4 - 64);   // lanes 0..34 handle float4 #64..98

    const float F = param[0];
    const float h = param[1];
    const float c = param[2];
    const float b = param[3];

    // chunked: block bb owns tiles [bb*TPB, (bb+1)*TPB); this wave's row in
    // tile t is (bb*TPB + t)*RPB + w.
    const long long rbase = ((long long)blockIdx.x * TPB * RPB + w) * ROW;
    const float* __restrict__ uw = u   + rbase;
    float*       __restrict__ ow = out + rbase;

    f4* si4 = (f4*)(si + w * ROW);
    const f4* so4 = (const f4*)(so + w * ROW);

    // ---- prologue: prefetch tile 0 into registers ----
    f4 r0 = ((const f4*)uw)[l];
    f4 r1 = {0.f, 0.f, 0.f, 0.f};
    if (second) r1 = ((const f4*)uw)[l + 64];

    for (int t = 0; t < TPB; ++t) {
        // stage current tile regs -> LDS (waits vmcnt for r0/r1 automatically)
        si4[l] = r0;
        if (second) si4[l + 64] = r1;
        WAVE_LDS_FENCE();

        // issue next tile's global loads now; vmcnt-wait lands at next
        // iteration's ds_write, hiding HBM latency under compute+store.
        if (t + 1 < TPB) {
            const f4* nxt = (const f4*)(uw + (long long)(t + 1) * EPB);
            r0 = nxt[l];
            if (second) r1 = nxt[l + 64];
        }

        // ---- lanes 0..35: one (group i) each -> dx[i] + dy[i][0..9] ----
        if (l < XX) {
            const int i = l;
            const float* __restrict__ row  = si + w * ROW;
            float*       __restrict__ orow = so + w * ROW;

            const float xi  = row[i];
            const float xp1 = row[(i + 1 < XX) ? i + 1 : i + 1 - XX];
            const float xm1 = row[(i >= 1) ? i - 1 : i + XX - 1];
            const float xm2 = row[(i >= 2) ? i - 2 : i + XX - 2];

            float y[XY];
            const float* __restrict__ yr = row + XX + i * XY;
            #pragma unroll
            for (int j = 0; j < XY; ++j) y[j] = yr[j];

            float sum = 0.0f;
            #pragma unroll
            for (int j = 0; j < XY; ++j) sum += y[j];

            orow[i] = (xp1 - xm2) * xm1 - xi + F - (h * c * 0.1f) * sum;

            const float add = h * 0.1f * xi;
            const float cb  = c * b;
            float* __restrict__ oyr = orow + XX + i * XY;
            #pragma unroll
            for (int j = 0; j < XY; ++j) {
                const int jp1 = (j + 1) % XY;          // compile-time under unroll
                const int jp2 = (j + 2) % XY;
                const int jm1 = (j + XY - 1) % XY;
                oyr[j] = c * (add - y[j]) - cb * y[jp1] * (y[jp2] - y[jm1]);
            }
        }
        WAVE_LDS_FENCE();

        // ---- store this tile: coalesced float4, NONTEMPORAL (round-6 best:
        // keep the write stream from evicting the L3-resident input) ----
        f4* __restrict__ o4 = (f4*)(ow + (long long)t * EPB);
        __builtin_nontemporal_store(so4[l], &o4[l]);
        if (second) __builtin_nontemporal_store(so4[l + 64], &o4[l + 64]);
    }
}

extern "C" void kernel_launch(void* const* d_in, const int* in_sizes, int n_in,
                              void* d_out, int out_size, void* d_ws, size_t ws_size,
                              hipStream_t stream) {
    // inputs: d_in[0] = t (int scalar, unused), d_in[1] = u (f32), d_in[2] = param (f32 x4)
    const float* u     = (const float*)d_in[1];
    const float* param = (const float*)d_in[2];
    float* out         = (float*)d_out;

    lorenz96_fs_kernel<<<NBLK, BLK, 0, stream>>>(u, param, out);
}

// Round 10
// 64.766 us; speedup vs baseline: 1.1062x; 1.0620x over previous
//
#include <hip/hip_runtime.h>

// ============================================================================
// Lorenz96 two-scale RHS. Memory-bound: 207.6 MB in + 207.6 MB out.
// VERIFIED-BEST config (round 6, 64.8 us = 6.4 TB/s payload ~= copy ceiling):
//  - 256-thr blocks (4 waves), 1 row per wave, wave-private LDS tiles,
//    no block barriers (wave-local lgkmcnt fences only).
//  - CACHED loads: input stays ~50% resident in the 256 MB Infinity Cache
//    across graph replays (FETCH ~105 MB < 207.6 MB).
//  - NONTEMPORAL stores: keeps the 207.6 MB write stream from evicting the
//    L3-resident input. (sc0sc1, NT-loads, NT-both, persistent blocks,
//    narrow direct stores: all tested, all slower.)
// ============================================================================

#define XX 36
#define XY 10
#define ROW 396               // XX * (XY + 1)
#define RPB 4                 // rows per block = 1 row per wave
#define BLK 256               // 4 waves -> 8 blocks/CU = 32 waves/CU
#define EPB (RPB * ROW)       // 1584 floats = 6336 B per tile
#define RV4 (ROW / 4)         // 99 float4 per row

typedef float f4 __attribute__((ext_vector_type(4)));

// wave-local ordering fence: DS ops of one wave execute in order, so this
// replaces __syncthreads() for wave-private tiles.
#define WAVE_LDS_FENCE() asm volatile("s_waitcnt lgkmcnt(0)" ::: "memory")

__global__ __launch_bounds__(BLK, 8)
void lorenz96_fs_kernel(const float* __restrict__ u,
                        const float* __restrict__ param,
                        float* __restrict__ out) {
    __shared__ float si[EPB];   // input tiles,  one 396-float slice per wave
    __shared__ float so[EPB];   // output tiles, one 396-float slice per wave

    const int tid = threadIdx.x;
    const int w   = tid >> 6;          // wave id 0..3
    const int l   = tid & 63;          // lane

    const float F = param[0];
    const float h = param[1];
    const float c = param[2];
    const float b = param[3];

    const long long rowg = (long long)blockIdx.x * RPB + w;   // this wave's row
    const long long gbase = rowg * ROW;

    // ---- wave loads its row: 99 float4, coalesced, CACHED (L3-resident) ----
    const f4* __restrict__ in4 = (const f4*)(u + gbase);
    f4* si4 = (f4*)(si + w * ROW);
    si4[l] = in4[l];
    if (l < RV4 - 64) si4[l + 64] = in4[l + 64];

    WAVE_LDS_FENCE();

    // ---- lanes 0..35: one (group i) each -> dx[i] + dy[i][0..9] ----
    if (l < XX) {
        const int i = l;
        const float* __restrict__ row  = si + w * ROW;
        float*       __restrict__ orow = so + w * ROW;

        const float xi  = row[i];
        const float xp1 = row[(i + 1 < XX) ? i + 1 : i + 1 - XX];
        const float xm1 = row[(i >= 1) ? i - 1 : i + XX - 1];
        const float xm2 = row[(i >= 2) ? i - 2 : i + XX - 2];

        float y[XY];
        const float* __restrict__ yr = row + XX + i * XY;
        #pragma unroll
        for (int j = 0; j < XY; ++j) y[j] = yr[j];

        float sum = 0.0f;
        #pragma unroll
        for (int j = 0; j < XY; ++j) sum += y[j];

        orow[i] = (xp1 - xm2) * xm1 - xi + F - (h * c * 0.1f) * sum;

        const float add = h * 0.1f * xi;
        const float cb  = c * b;
        float* __restrict__ oyr = orow + XX + i * XY;
        #pragma unroll
        for (int j = 0; j < XY; ++j) {
            const int jp1 = (j + 1) % XY;          // compile-time under unroll
            const int jp2 = (j + 2) % XY;
            const int jm1 = (j + XY - 1) % XY;
            oyr[j] = c * (add - y[j]) - cb * y[jp1] * (y[jp2] - y[jm1]);
        }
    }

    WAVE_LDS_FENCE();

    // ---- wave stores its row: 99 float4, coalesced, NONTEMPORAL ----
    const f4* __restrict__ so4 = (const f4*)(so + w * ROW);
    f4* __restrict__ o4 = (f4*)(out + gbase);
    __builtin_nontemporal_store(so4[l], &o4[l]);
    if (l < RV4 - 64) __builtin_nontemporal_store(so4[l + 64], &o4[l + 64]);
}

extern "C" void kernel_launch(void* const* d_in, const int* in_sizes, int n_in,
                              void* d_out, int out_size, void* d_ws, size_t ws_size,
                              hipStream_t stream) {
    // inputs: d_in[0] = t (int scalar, unused), d_in[1] = u (f32), d_in[2] = param (f32 x4)
    const float* u     = (const float*)d_in[1];
    const float* param = (const float*)d_in[2];
    float* out         = (float*)d_out;

    const int nrows   = in_sizes[1] / ROW;     // 131072
    const int nblocks = nrows / RPB;           // 32768

    lorenz96_fs_kernel<<<nblocks, BLK, 0, stream>>>(u, param, out);
}